// Round 5
// baseline (126.644 us; speedup 1.0000x reference)
//
#include <hip/hip_runtime.h>

#define TPB    256
#define CHUNKS 16     // blocks per batch along T (2048 blocks total at B=128)
#define NACC   21     // 16 D[i][j] + 4 S1[i] + 1 denom
#define NPERM  24

__constant__ int c_perm[NPERM][4] = {
    {0,1,2,3},{0,1,3,2},{0,2,1,3},{0,2,3,1},{0,3,1,2},{0,3,2,1},
    {1,0,2,3},{1,0,3,2},{1,2,0,3},{1,2,3,0},{1,3,0,2},{1,3,2,0},
    {2,0,1,3},{2,0,3,1},{2,1,0,3},{2,1,3,0},{2,3,0,1},{2,3,1,0},
    {3,0,1,2},{3,0,2,1},{3,1,0,2},{3,1,2,0},{3,2,0,1},{3,2,1,0}
};

// Fused single-launch PIT loss, fence-free.
//   bce[b,t,i,j] = -lq_i + t_j*(lq_i - lp_i)  =>  per batch need only
//   D[i][j]=sum m*t_j*(lq_i-lp_i) (16), S1[i]=sum m*lq_i (4), dn=sum m (1).
// Cross-block handoff uses ONLY device-scope atomics (RMWs complete at the
// device coherence point -> no __threadfence / L2 writeback needed, which is
// what made R3 3x slower). Ordering: the 21 gacc atomicAdds are issued by
// lanes 0..20 of wave 0 (one instruction); consuming their return value in an
// asm compiler barrier forces s_waitcnt vmcnt(0) before the ticket atomic.
__global__ __launch_bounds__(TPB) void pit_fused(
    const float* __restrict__ pred, const float* __restrict__ target,
    const float* __restrict__ mask, float* __restrict__ gacc,
    unsigned int* __restrict__ ticket, float* __restrict__ out,
    int T, int nblk, int B)
{
    const int b      = blockIdx.x / CHUNKS;
    const int chunk  = blockIdx.x - b * CHUNKS;
    const int tPerBlock = (T + CHUNKS - 1) / CHUNKS;
    const int tid    = threadIdx.x;
    const int base   = chunk * tPerBlock;
    const int tEnd   = min(base + tPerBlock, T);

    const float4* p4  = (const float4*)pred   + (size_t)b * T;
    const float4* t4  = (const float4*)target + (size_t)b * T;
    const float* mrow = mask + (size_t)b * T;

    float D[4][4] = {{0.f,0.f,0.f,0.f},{0.f,0.f,0.f,0.f},
                     {0.f,0.f,0.f,0.f},{0.f,0.f,0.f,0.f}};
    float S1[4] = {0.f,0.f,0.f,0.f};
    float dn = 0.f;

    const float lo = 1e-7f;
    const float hi = 1.0f - 1e-7f;

    auto compute = [&](float4 pv, float4 tv, float m) {
        float pp[4] = {pv.x, pv.y, pv.z, pv.w};
        float tt[4] = {tv.x, tv.y, tv.z, tv.w};
        float lp[4], lq[4];
        #pragma unroll
        for (int s = 0; s < 4; ++s) {
            float p = fminf(fmaxf(pp[s], lo), hi);
            lp[s] = __logf(p);
            lq[s] = __logf(1.0f - p);
        }
        dn += m;
        float mt[4];
        #pragma unroll
        for (int j = 0; j < 4; ++j) mt[j] = m * tt[j];
        #pragma unroll
        for (int i = 0; i < 4; ++i) {
            S1[i] = fmaf(m, lq[i], S1[i]);
            float d = lq[i] - lp[i];
            #pragma unroll
            for (int j = 0; j < 4; ++j) D[i][j] = fmaf(d, mt[j], D[i][j]);
        }
    };

    const int t0 = base + tid;
    if (t0 + 3 * TPB < tEnd) {
        // Fast path (exact at T=16384: 4 rows/thread): hoist all 12 loads.
        float4 pv[4], tv[4];
        float  mv[4];
        #pragma unroll
        for (int k = 0; k < 4; ++k) {
            pv[k] = p4[t0 + k * TPB];
            tv[k] = t4[t0 + k * TPB];
        }
        #pragma unroll
        for (int k = 0; k < 4; ++k) mv[k] = mrow[t0 + k * TPB];
        #pragma unroll
        for (int k = 0; k < 4; ++k) compute(pv[k], tv[k], mv[k]);
    } else {
        for (int t = t0; t < tEnd; t += TPB)
            compute(p4[t], t4[t], mrow[t]);
    }

    float acc[NACC];
    #pragma unroll
    for (int i = 0; i < 4; ++i)
        #pragma unroll
        for (int j = 0; j < 4; ++j) acc[i * 4 + j] = D[i][j];
    #pragma unroll
    for (int i = 0; i < 4; ++i) acc[16 + i] = S1[i];
    acc[20] = dn;

    // wave-64 butterfly reduction for each accumulator
    #pragma unroll
    for (int k = 0; k < NACC; ++k) {
        float v = acc[k];
        #pragma unroll
        for (int off = 32; off > 0; off >>= 1)
            v += __shfl_xor(v, off, 64);
        acc[k] = v;
    }

    __shared__ float sred[TPB / 64][NACC];
    __shared__ bool s_last;
    const int wave = tid >> 6;
    const int lane = tid & 63;
    if (lane == 0) {
        #pragma unroll
        for (int k = 0; k < NACC; ++k) sred[wave][k] = acc[k];
    }
    __syncthreads();

    if (wave == 0) {
        float junk = 0.f;
        if (lane < NACC) {
            float v = 0.f;
            #pragma unroll
            for (int w = 0; w < TPB / 64; ++w) v += sred[w][lane];
            // one global_atomic_add instruction, lanes 0..20 active
            junk = atomicAdd(&gacc[b * NACC + lane], v);
        }
        // Consume the returned old value: forces s_waitcnt vmcnt(0) (the adds
        // are complete at the device coherence point) with NO cache ops.
        asm volatile("" :: "v"(junk) : "memory");
        if (lane == 0) {
            unsigned int prev = atomicAdd(ticket, 1u);
            s_last = (prev == (unsigned int)(nblk - 1));
        }
    }
    __syncthreads();
    if (!s_last) return;

    // --- finalize (last block only; thread b handles batch b) ---
    float minv = 0.f;
    if (tid < B) {
        float A[NACC];
        #pragma unroll
        for (int k = 0; k < NACC; ++k)
            A[k] = atomicAdd(&gacc[tid * NACC + k], 0.0f);  // coherent read
        const float inv = 1.0f / (4.0f * A[20]);   // 1/(S*denom)
        float C[4][4];
        #pragma unroll
        for (int i = 0; i < 4; ++i)
            #pragma unroll
            for (int j = 0; j < 4; ++j)
                C[i][j] = (A[i * 4 + j] - A[16 + i]) * inv;

        minv = 3.4e38f;
        int mini = 0;
        #pragma unroll
        for (int p = 0; p < NPERM; ++p) {
            float v = C[0][c_perm[p][0]] + C[1][c_perm[p][1]]
                    + C[2][c_perm[p][2]] + C[3][c_perm[p][3]];
            if (v < minv) { minv = v; mini = p; }  // strict <: argmin rule
        }
        #pragma unroll
        for (int i = 0; i < 4; ++i)
            out[1 + tid * 4 + i] = (float)c_perm[mini][i];
    }

    // block-reduce sum of per-batch min losses (inactive lanes contribute 0)
    float v = (tid < B) ? minv : 0.f;
    #pragma unroll
    for (int off = 32; off > 0; off >>= 1)
        v += __shfl_xor(v, off, 64);
    __shared__ float ssum[TPB / 64];
    if (lane == 0) ssum[wave] = v;
    __syncthreads();
    if (tid == 0) {
        float s = 0.f;
        #pragma unroll
        for (int w = 0; w < TPB / 64; ++w) s += ssum[w];
        out[0] = s / (float)B;
    }
}

extern "C" void kernel_launch(void* const* d_in, const int* in_sizes, int n_in,
                              void* d_out, int out_size, void* d_ws, size_t ws_size,
                              hipStream_t stream)
{
    const float* pred   = (const float*)d_in[0];
    const float* target = (const float*)d_in[1];
    const float* mask   = (const float*)d_in[2];
    float* out = (float*)d_out;

    const int B = (out_size - 1) / 4;      // out = [loss] + [B,4] perms
    const int T = in_sizes[2] / B;         // mask is [B,T]
    const int nblk = B * CHUNKS;

    float* gacc = (float*)d_ws;                         // B*NACC floats
    const size_t gacc_bytes = ((size_t)B * NACC * 4 + 127) / 128 * 128;
    unsigned int* ticket = (unsigned int*)((char*)d_ws + gacc_bytes);

    // ws is poisoned 0xAA before every launch: zero accumulators + ticket
    hipMemsetAsync(d_ws, 0, gacc_bytes + 128, stream);

    pit_fused<<<nblk, TPB, 0, stream>>>(pred, target, mask, gacc, ticket,
                                        out, T, nblk, B);
}

// Round 6
// 111.479 us; speedup vs baseline: 1.1360x; 1.1360x over previous
//
#include <hip/hip_runtime.h>

#define TPB    256
#define CHUNKS 8      // blocks per batch along T; 8 rows/thread exact at T=16384
#define ITERS  8      // T / (CHUNKS*TPB) for the canonical shape
#define NACC   21     // 16 D[i][j] + 4 S1[i] + 1 denom
#define NPERM  24

__constant__ int c_perm[NPERM][4] = {
    {0,1,2,3},{0,1,3,2},{0,2,1,3},{0,2,3,1},{0,3,1,2},{0,3,2,1},
    {1,0,2,3},{1,0,3,2},{1,2,0,3},{1,2,3,0},{1,3,0,2},{1,3,2,0},
    {2,0,1,3},{2,0,3,1},{2,1,0,3},{2,1,3,0},{2,3,0,1},{2,3,1,0},
    {3,0,1,2},{3,0,2,1},{3,1,0,2},{3,1,2,0},{3,2,0,1},{3,2,1,0}
};

// Stage 1: per-(batch, T-chunk) partials of the 21 accumulators.
//   bce[b,t,i,j] = -lq_i + t_j*(lq_i - lp_i)  =>
//   D[i][j]=sum m*t_j*(lq_i-lp_i); S1[i]=sum m*lq_i; dn=sum m.
// R5 diagnosis: compiler allocated 32 VGPRs -> every hoisted load was sunk
// to its use; waves ran with ~1 load in flight (duration invariant to L3
// warmth proved latency-bound, not BW-bound). Fix: amdgpu_waves_per_eu(4)
// raises the register budget to 128 so the full-chunk load hoist SURVIVES:
// all 24 float4 + 8 scalar loads issued before any compute.
__global__ __launch_bounds__(TPB) __attribute__((amdgpu_waves_per_eu(4)))
void pit_partial(
    const float* __restrict__ pred, const float* __restrict__ target,
    const float* __restrict__ mask, float* __restrict__ partial, int T, int nblk)
{
    const int b      = blockIdx.x / CHUNKS;
    const int chunk  = blockIdx.x - b * CHUNKS;
    const int tPerBlock = (T + CHUNKS - 1) / CHUNKS;
    const int tid    = threadIdx.x;
    const int base   = chunk * tPerBlock;
    const int tEnd   = min(base + tPerBlock, T);

    const float4* p4  = (const float4*)pred   + (size_t)b * T;
    const float4* t4  = (const float4*)target + (size_t)b * T;
    const float* mrow = mask + (size_t)b * T;

    float D[4][4] = {{0.f,0.f,0.f,0.f},{0.f,0.f,0.f,0.f},
                     {0.f,0.f,0.f,0.f},{0.f,0.f,0.f,0.f}};
    float S1[4] = {0.f,0.f,0.f,0.f};
    float dn = 0.f;

    const float lo = 1e-7f;
    const float hi = 1.0f - 1e-7f;

    auto compute = [&](float4 pv, float4 tv, float m) {
        float pp[4] = {pv.x, pv.y, pv.z, pv.w};
        float tt[4] = {tv.x, tv.y, tv.z, tv.w};
        float lp[4], lq[4];
        #pragma unroll
        for (int s = 0; s < 4; ++s) {
            float p = fminf(fmaxf(pp[s], lo), hi);
            lp[s] = __logf(p);
            lq[s] = __logf(1.0f - p);
        }
        dn += m;
        float mt[4];
        #pragma unroll
        for (int j = 0; j < 4; ++j) mt[j] = m * tt[j];
        #pragma unroll
        for (int i = 0; i < 4; ++i) {
            S1[i] = fmaf(m, lq[i], S1[i]);
            float d = lq[i] - lp[i];
            #pragma unroll
            for (int j = 0; j < 4; ++j) D[i][j] = fmaf(d, mt[j], D[i][j]);
        }
    };

    const int t0 = base + tid;
    if (t0 + (ITERS - 1) * TPB < tEnd) {
        // Full chunk (the only path at T=16384): issue ALL loads, then compute.
        // Payload = 8*(4+4)+8 = 72 VGPRs; fits the 128-VGPR budget from
        // waves_per_eu(4), so the allocator cannot sink these.
        float4 pv[ITERS], tv[ITERS];
        float  mv[ITERS];
        #pragma unroll
        for (int k = 0; k < ITERS; ++k) pv[k] = p4[t0 + k * TPB];
        #pragma unroll
        for (int k = 0; k < ITERS; ++k) tv[k] = t4[t0 + k * TPB];
        #pragma unroll
        for (int k = 0; k < ITERS; ++k) mv[k] = mrow[t0 + k * TPB];
        #pragma unroll
        for (int k = 0; k < ITERS; ++k) compute(pv[k], tv[k], mv[k]);
    } else {
        for (int t = t0; t < tEnd; t += TPB)
            compute(p4[t], t4[t], mrow[t]);
    }

    float acc[NACC];
    #pragma unroll
    for (int i = 0; i < 4; ++i)
        #pragma unroll
        for (int j = 0; j < 4; ++j) acc[i * 4 + j] = D[i][j];
    #pragma unroll
    for (int i = 0; i < 4; ++i) acc[16 + i] = S1[i];
    acc[20] = dn;

    // wave-64 butterfly reduction for each accumulator
    #pragma unroll
    for (int k = 0; k < NACC; ++k) {
        float v = acc[k];
        #pragma unroll
        for (int off = 32; off > 0; off >>= 1)
            v += __shfl_xor(v, off, 64);
        acc[k] = v;
    }

    __shared__ float sred[TPB / 64][NACC];
    const int wave = tid >> 6;
    const int lane = tid & 63;
    if (lane == 0) {
        #pragma unroll
        for (int k = 0; k < NACC; ++k) sred[wave][k] = acc[k];
    }
    __syncthreads();
    if (tid < NACC) {
        float v = 0.f;
        #pragma unroll
        for (int w = 0; w < TPB / 64; ++w) v += sred[w][tid];
        partial[(size_t)tid * nblk + blockIdx.x] = v;  // transposed layout
    }
}

// Stage 2: one block; thread b sums its CHUNKS partials (two float4 loads per
// accumulator via the transposed layout), builds C[4][4], scans the 24 perms
// (strict < = argmin first-occurrence rule), writes best perm as floats,
// block-reduces the mean loss.
__global__ __launch_bounds__(128) void pit_final(
    const float* __restrict__ partial, float* __restrict__ out, int B, int nblk)
{
    const int b = threadIdx.x;
    float minv = 0.f;

    if (b < B) {
        float A[NACC];
        #pragma unroll
        for (int k = 0; k < NACC; ++k) {
            const float4* src =
                (const float4*)(partial + (size_t)k * nblk + b * CHUNKS);
            float s = 0.f;
            #pragma unroll
            for (int q = 0; q < CHUNKS / 4; ++q) {
                float4 u = src[q];
                s += (u.x + u.y) + (u.z + u.w);
            }
            A[k] = s;
        }
        const float inv = 1.0f / (4.0f * A[20]);   // 1/(S*denom)
        float C[4][4];
        #pragma unroll
        for (int i = 0; i < 4; ++i)
            #pragma unroll
            for (int j = 0; j < 4; ++j)
                C[i][j] = (A[i * 4 + j] - A[16 + i]) * inv;

        minv = 3.4e38f;
        int mini = 0;
        #pragma unroll
        for (int p = 0; p < NPERM; ++p) {
            float v = C[0][c_perm[p][0]] + C[1][c_perm[p][1]]
                    + C[2][c_perm[p][2]] + C[3][c_perm[p][3]];
            if (v < minv) { minv = v; mini = p; }  // strict <: argmin rule
        }
        #pragma unroll
        for (int i = 0; i < 4; ++i)
            out[1 + b * 4 + i] = (float)c_perm[mini][i];
    }

    // block-reduce sum of per-batch min losses
    float v = minv;
    #pragma unroll
    for (int off = 32; off > 0; off >>= 1)
        v += __shfl_xor(v, off, 64);
    __shared__ float ssum[16];
    const int wave = threadIdx.x >> 6;
    const int nwaves = blockDim.x >> 6;
    if ((threadIdx.x & 63) == 0) ssum[wave] = v;
    __syncthreads();
    if (threadIdx.x == 0) {
        float s = 0.f;
        for (int w = 0; w < nwaves; ++w) s += ssum[w];
        out[0] = s / (float)B;
    }
}

extern "C" void kernel_launch(void* const* d_in, const int* in_sizes, int n_in,
                              void* d_out, int out_size, void* d_ws, size_t ws_size,
                              hipStream_t stream)
{
    const float* pred   = (const float*)d_in[0];
    const float* target = (const float*)d_in[1];
    const float* mask   = (const float*)d_in[2];
    float* out     = (float*)d_out;
    float* partial = (float*)d_ws;   // NACC * nblk floats = 86 KB

    const int B = (out_size - 1) / 4;      // out = [loss] + [B,4] perms
    const int T = in_sizes[2] / B;         // mask is [B,T]
    const int nblk = B * CHUNKS;

    pit_partial<<<nblk, TPB, 0, stream>>>(pred, target, mask, partial, T, nblk);
    pit_final<<<1, 128, 0, stream>>>(partial, out, B, nblk);
}